// Round 1
// 284.733 us; speedup vs baseline: 1.0740x; 1.0740x over previous
//
#include <hip/hip_runtime.h>
#include <hip/hip_bf16.h>

#define N_NODES 100000
#define N_EDGES 1600000
#define IN_DIM 48
#define OUT_DIM 128
#define K1 144                 // 3*IN_DIM
#define NSEG (2 * N_NODES)     // 200000 segments (node x {mi,mo})
#define NMSG (2 * N_EDGES)     // 3.2M directed messages
#define NBIN 784               // coarse bins: bin = seg >> 8  (784*256 >= NSEG)
#define BINCAP 4608            // per-bin region capacity: mean 4082 + ~8 sigma
#define EPB 4096               // edges per binscat block (391 blocks ~ 1.5/CU)
#define XROW 64                // padded xb row: 64 u16 = 128B = 1 cache line

typedef unsigned short u16;
typedef unsigned long long u64;
typedef __attribute__((ext_vector_type(8))) short short8;
typedef __attribute__((ext_vector_type(4))) float f32x4;
typedef __attribute__((ext_vector_type(4))) unsigned uint4v;

// round-to-nearest-even f32 -> bf16 bits
static __device__ __forceinline__ u16 f2bf(float f) {
  unsigned u = __float_as_uint(f);
  unsigned r = (u + 0x7fffu + ((u >> 16) & 1u)) >> 16;
  return (u16)r;
}
// fast tanh: 1 - 2/(e^{2x}+1)  (v_exp_f32 + v_rcp_f32, ~1e-6 abs error)
static __device__ __forceinline__ float ftanh(float x) {
  return 1.f - 2.f * __builtin_amdgcn_rcpf(__expf(2.f * x) + 1.f);
}

// ---------------------------------------------------------------------------
// Stage 0: dtype conversions (fp32 -> bf16)
// ---------------------------------------------------------------------------
__global__ __launch_bounds__(256) void prep_w_kernel(
    const float* __restrict__ W1, const float* __restrict__ W2,
    u16* __restrict__ W1b, u16* __restrict__ W2b)
{
  int i = blockIdx.x * 256 + threadIdx.x;
  if (i < OUT_DIM * K1) {
    W1b[i] = f2bf(W1[i]);
  } else if (i < OUT_DIM * K1 + OUT_DIM * OUT_DIM) {
    int j = i - OUT_DIM * K1;
    W2b[j] = f2bf(W2[j]);
  }
}

// xb rows padded to 128B (XROW u16): dims 0..47 real, 48..63 zero.
__global__ __launch_bounds__(256) void prep_x_kernel(
    const float* __restrict__ x, u16* __restrict__ xb)
{
  int i = blockIdx.x * 256 + threadIdx.x;   // over N_NODES*XROW
  if (i < N_NODES * XROW) {
    int node = i >> 6;
    int d = i & 63;
    xb[i] = (d < IN_DIM) ? f2bf(x[node * IN_DIM + d]) : (u16)0;
  }
}

// ---------------------------------------------------------------------------
// Phase A: binscat — partition 3.2M messages into 784 coarse bins.
// Record (8B): .x = (seg_low << 24) | src, .y = fp32 w bits.
//   dir0 (mi): dst=col, src=row    dir1 (mo): dst=row, src=col
// ---------------------------------------------------------------------------
__global__ __launch_bounds__(256) void binscat_kernel(
    const int* __restrict__ eidx, const float* __restrict__ ea,
    int* __restrict__ bin_cursor, int2* __restrict__ bkt)
{
  __shared__ int hist[NBIN];   // pass1: counts; then: within-bin write cursor
  for (int i = threadIdx.x; i < NBIN; i += 256) hist[i] = 0;
  __syncthreads();

  const int e0 = blockIdx.x * EPB;
  const int e1 = min(e0 + EPB, N_EDGES);

  for (int e = e0 + threadIdx.x; e < e1; e += 256) {
    int row = eidx[e];
    int col = eidx[N_EDGES + e];
    atomicAdd(&hist[col >> 7], 1);              // seg0 = col*2   -> bin seg0>>8
    atomicAdd(&hist[(row * 2 + 1) >> 8], 1);    // seg1 = row*2+1
  }
  __syncthreads();

  for (int b = threadIdx.x; b < NBIN; b += 256) {
    int c = hist[b];
    hist[b] = c ? atomicAdd(&bin_cursor[b], c) : 0;
  }
  __syncthreads();

  for (int e = e0 + threadIdx.x; e < e1; e += 256) {
    int row = eidx[e];
    int col = eidx[N_EDGES + e];
    int w = __float_as_int(ea[e]);
    int seg0 = col * 2;
    int seg1 = row * 2 + 1;
    int s0 = atomicAdd(&hist[seg0 >> 8], 1);
    if (s0 < BINCAP)
      bkt[(size_t)(seg0 >> 8) * BINCAP + s0] =
          make_int2(((seg0 & 255) << 24) | row, w);
    int s1 = atomicAdd(&hist[seg1 >> 8], 1);
    if (s1 < BINCAP)
      bkt[(size_t)(seg1 >> 8) * BINCAP + s1] =
          make_int2(((seg1 & 255) << 24) | col, w);
  }
}

// ---------------------------------------------------------------------------
// binscan: 1-block exclusive scan of the 784 bin counts -> bin_base
// ---------------------------------------------------------------------------
__global__ __launch_bounds__(256) void binscan_kernel(
    const int* __restrict__ bin_cursor, int* __restrict__ bin_base)
{
  __shared__ int sh[256];
  int carry = 0;
  for (int base = 0; base < NBIN; base += 256) {
    int idx = base + threadIdx.x;
    int v = (idx < NBIN) ? min(bin_cursor[idx], BINCAP) : 0;
    sh[threadIdx.x] = v;
    __syncthreads();
#pragma unroll
    for (int off = 1; off < 256; off <<= 1) {
      int t = (threadIdx.x >= off) ? sh[threadIdx.x - off] : 0;
      __syncthreads();
      sh[threadIdx.x] += t;
      __syncthreads();
    }
    if (idx < NBIN) bin_base[idx] = carry + (threadIdx.x ? sh[threadIdx.x - 1] : 0);
    carry += sh[255];
    __syncthreads();
  }
}

// ---------------------------------------------------------------------------
// Phase B: binsort — one block per bin. LDS hist over the bin's 256 segments,
// LDS scan, write exact per-segment offsets + 4B-packed CSR
// (rec = src<<15 | w_bf16_lo15; ea >= 0 so the bf16 sign bit is always 0).
// ---------------------------------------------------------------------------
__global__ __launch_bounds__(256) void binsort_kernel(
    const int2* __restrict__ bkt, const int* __restrict__ bin_cursor,
    const int* __restrict__ bin_base, unsigned* __restrict__ csr,
    int* __restrict__ offsets)
{
  __shared__ int hist[256];
  __shared__ int sh[256];
  const int b = blockIdx.x;
  const int cnt = min(bin_cursor[b], BINCAP);
  const int2* recs = bkt + (size_t)b * BINCAP;
  const int t = threadIdx.x;

  hist[t] = 0;
  __syncthreads();
  for (int j = t; j < cnt; j += 256)
    atomicAdd(&hist[(unsigned)recs[j].x >> 24], 1);
  __syncthreads();

  sh[t] = hist[t];
  __syncthreads();
#pragma unroll
  for (int off = 1; off < 256; off <<= 1) {
    int v = (t >= off) ? sh[t - off] : 0;
    __syncthreads();
    sh[t] += v;
    __syncthreads();
  }
  const int base = bin_base[b];
  const int excl = base + (t ? sh[t - 1] : 0);
  offsets[b * 256 + t] = excl;
  hist[t] = excl;
  __syncthreads();

  for (int j = t; j < cnt; j += 256) {
    int2 r = recs[j];
    int segl = (unsigned)r.x >> 24;
    unsigned src = (unsigned)r.x & 0xFFFFFFu;
    unsigned wb = f2bf(__int_as_float(r.y));
    int slot = atomicAdd(&hist[segl], 1);
    csr[slot] = (src << 15) | (wb & 0x7FFFu);
  }
}

// ---------------------------------------------------------------------------
// Gather (redesigned): 8 segments per wave, 8 lanes per segment.
// Lane r8 owns dims [8*r8, 8*r8+8): one aligned dwordx4 (=1 cache line per
// record across the group). Uniform predicated loop to the wave-max segment
// length; inactive slots clamp to csr[0] (valid, finite) with w=0.
// No cross-lane reduce: each group's registers are its output row.
// Mseg layout: [node][0..47]=mi, [48..95]=mo (bf16) — unchanged.
// ---------------------------------------------------------------------------
__global__ __launch_bounds__(256) void gather_kernel(
    const unsigned* __restrict__ csr, const int* __restrict__ offs,
    const uint4v* __restrict__ xb4, u16* __restrict__ Mseg)
{
  const int lane = threadIdx.x & 63;
  const int g    = lane >> 3;                       // segment group 0..7
  const int r8   = lane & 7;                        // dim block within row
  const int seg  = blockIdx.x * 32 + (threadIdx.x >> 6) * 8 + g;

  const int beg = offs[seg];
  const int n   = offs[seg + 1] - beg;

  // wave-max of n (n is uniform within each 8-lane group -> 3 xor steps)
  int kmax = n;
  kmax = max(kmax, __shfl_xor(kmax, 8, 64));
  kmax = max(kmax, __shfl_xor(kmax, 16, 64));
  kmax = max(kmax, __shfl_xor(kmax, 32, 64));

  float a[8];
#pragma unroll
  for (int c = 0; c < 8; ++c) a[c] = 0.f;

  for (int it = 0; it < kmax; it += 2) {
    const bool p = (it     < n);
    const bool q = (it + 1 < n);
    unsigned rp = csr[p ? beg + it     : 0];
    unsigned rq = csr[q ? beg + it + 1 : 0];
    float wp = p ? __uint_as_float((rp & 0x7FFFu) << 16) : 0.f;
    float wq = q ? __uint_as_float((rq & 0x7FFFu) << 16) : 0.f;
    uint4v vp = xb4[(rp >> 15) * 8 + r8];
    uint4v vq = xb4[(rq >> 15) * 8 + r8];
#pragma unroll
    for (int c = 0; c < 4; ++c) {
      a[2 * c]     = fmaf(__uint_as_float(vp[c] << 16),         wp, a[2 * c]);
      a[2 * c + 1] = fmaf(__uint_as_float(vp[c] & 0xFFFF0000u), wp, a[2 * c + 1]);
    }
#pragma unroll
    for (int c = 0; c < 4; ++c) {
      a[2 * c]     = fmaf(__uint_as_float(vq[c] << 16),         wq, a[2 * c]);
      a[2 * c + 1] = fmaf(__uint_as_float(vq[c] & 0xFFFF0000u), wq, a[2 * c + 1]);
    }
  }

  if (r8 < 6) {                                     // dims 48..63 are pad
    unsigned d[4];
#pragma unroll
    for (int c = 0; c < 4; ++c)
      d[c] = (unsigned)f2bf(a[2 * c]) | ((unsigned)f2bf(a[2 * c + 1]) << 16);
    uint4v o = {d[0], d[1], d[2], d[3]};
    *(uint4v*)(Mseg + (size_t)seg * IN_DIM + r8 * 8) = o;
  }
}

// ---------------------------------------------------------------------------
// Stage 2: fused 2-layer MLP with MFMA 16x16x32 bf16.
// ---------------------------------------------------------------------------
static __device__ __forceinline__ short8 loadM(
    const u16* __restrict__ Mseg, const u16* __restrict__ xb, int m, int k)
{
  short8 r = {0, 0, 0, 0, 0, 0, 0, 0};
  if (k < 96) {
    r = *(const short8*)(Mseg + m * 96 + k);
  } else if (k < K1) {
    r = *(const short8*)(xb + m * XROW + (k - 96));   // padded 128B rows
  }
  return r;
}

__global__ __launch_bounds__(256) void mlp_kernel(
    const u16* __restrict__ Mseg, const u16* __restrict__ xb,
    const u16* __restrict__ W1b, const float* __restrict__ b1,
    const u16* __restrict__ W2b, const float* __restrict__ b2,
    float* __restrict__ out)
{
  __shared__ __align__(16) u16 hbuf[4][32][136];
  const int wave = threadIdx.x >> 6;
  const int lane = threadIdx.x & 63;
  const int col  = lane & 15;
  const int quad = lane >> 4;
  const int kq   = quad * 8;
  const int nodeBase = (blockIdx.x * 4 + wave) * 32;

  const int ma0 = min(nodeBase + col,      N_NODES - 1);
  const int ma1 = min(nodeBase + 16 + col, N_NODES - 1);

  f32x4 acc[2][8];
#pragma unroll
  for (int mt = 0; mt < 2; ++mt)
#pragma unroll
    for (int nt = 0; nt < 8; ++nt) acc[mt][nt] = (f32x4){0.f, 0.f, 0.f, 0.f};

#pragma unroll
  for (int ks = 0; ks < 5; ++ks) {
    const int k = ks * 32 + kq;
    short8 a0 = loadM(Mseg, xb, ma0, k);
    short8 a1 = loadM(Mseg, xb, ma1, k);
#pragma unroll
    for (int nt = 0; nt < 8; ++nt) {
      short8 b = {0, 0, 0, 0, 0, 0, 0, 0};
      if (k < K1)
        b = *(const short8*)(W1b + (nt * 16 + col) * K1 + k);
      acc[0][nt] = __builtin_amdgcn_mfma_f32_16x16x32_bf16(a0, b, acc[0][nt], 0, 0, 0);
      acc[1][nt] = __builtin_amdgcn_mfma_f32_16x16x32_bf16(a1, b, acc[1][nt], 0, 0, 0);
    }
  }

#pragma unroll
  for (int mt = 0; mt < 2; ++mt)
#pragma unroll
    for (int nt = 0; nt < 8; ++nt) {
      const int n = nt * 16 + col;
      const float bb = b1[n];
#pragma unroll
      for (int rg = 0; rg < 4; ++rg) {
        const int rowl = mt * 16 + quad * 4 + rg;
        hbuf[wave][rowl][n] = f2bf(ftanh(acc[mt][nt][rg] + bb));
      }
    }
  __syncthreads();

  f32x4 acc2[2][8];
#pragma unroll
  for (int mt = 0; mt < 2; ++mt)
#pragma unroll
    for (int nt = 0; nt < 8; ++nt) acc2[mt][nt] = (f32x4){0.f, 0.f, 0.f, 0.f};

#pragma unroll
  for (int ks = 0; ks < 4; ++ks) {
    const int k = ks * 32 + kq;
    short8 a0 = *(const short8*)&hbuf[wave][col][k];
    short8 a1 = *(const short8*)&hbuf[wave][16 + col][k];
#pragma unroll
    for (int nt = 0; nt < 8; ++nt) {
      short8 b = *(const short8*)(W2b + (nt * 16 + col) * OUT_DIM + k);
      acc2[0][nt] = __builtin_amdgcn_mfma_f32_16x16x32_bf16(a0, b, acc2[0][nt], 0, 0, 0);
      acc2[1][nt] = __builtin_amdgcn_mfma_f32_16x16x32_bf16(a1, b, acc2[1][nt], 0, 0, 0);
    }
  }

#pragma unroll
  for (int mt = 0; mt < 2; ++mt)
#pragma unroll
    for (int nt = 0; nt < 8; ++nt) {
      const int n = nt * 16 + col;
      const float bb = b2[n];
#pragma unroll
      for (int rg = 0; rg < 4; ++rg) {
        const int node = nodeBase + mt * 16 + quad * 4 + rg;
        if (node < N_NODES)
          out[node * OUT_DIM + n] = ftanh(acc2[mt][nt][rg] + bb);
      }
    }
}

extern "C" void kernel_launch(void* const* d_in, const int* in_sizes, int n_in,
                              void* d_out, int out_size, void* d_ws, size_t ws_size,
                              hipStream_t stream) {
  const float* x   = (const float*)d_in[0];
  const int* eidx  = (const int*)d_in[1];
  const float* ea  = (const float*)d_in[2];
  const float* W1  = (const float*)d_in[3];
  const float* b1  = (const float*)d_in[4];
  const float* W2  = (const float*)d_in[5];
  const float* b2  = (const float*)d_in[6];
  float* out = (float*)d_out;

  // workspace layout (16B-aligned), ~74.6 MB total:
  char* p = (char*)d_ws;
  u16* Mseg       = (u16*)p;      p += (size_t)NSEG * IN_DIM * 2;      // 19.2 MB
  u16* xb         = (u16*)p;      p += (size_t)N_NODES * XROW * 2;     // 12.8 MB (padded rows)
  u16* W1b        = (u16*)p;      p += OUT_DIM * K1 * 2;
  u16* W2b        = (u16*)p;      p += OUT_DIM * OUT_DIM * 2;
  int* bin_cursor = (int*)p;      p += 1024 * 4;
  int* bin_base   = (int*)p;      p += 1024 * 4;
  int* offsets    = (int*)p;      p += (size_t)(NBIN * 256 + 16) * 4;  //  0.8 MB
  int2* bkt       = (int2*)p;     p += (size_t)NBIN * BINCAP * 8;      // 28.9 MB
  unsigned* csr   = (unsigned*)p; p += (size_t)NMSG * 4;               // 12.8 MB

  hipMemsetAsync(bin_cursor, 0, 1024 * 4, stream);

  int prep_elems = OUT_DIM * K1 + OUT_DIM * OUT_DIM;
  prep_w_kernel<<<(prep_elems + 255) / 256, 256, 0, stream>>>(W1, W2, W1b, W2b);
  prep_x_kernel<<<(N_NODES * XROW + 255) / 256, 256, 0, stream>>>(x, xb);

  binscat_kernel<<<(N_EDGES + EPB - 1) / EPB, 256, 0, stream>>>(
      eidx, ea, bin_cursor, bkt);
  binscan_kernel<<<1, 256, 0, stream>>>(bin_cursor, bin_base);
  binsort_kernel<<<NBIN, 256, 0, stream>>>(bkt, bin_cursor, bin_base, csr, offsets);

  gather_kernel<<<NSEG / 32, 256, 0, stream>>>(
      csr, offsets, (const uint4v*)xb, Mseg);

  int nblocks = (N_NODES + 127) / 128;
  mlp_kernel<<<nblocks, 256, 0, stream>>>(Mseg, xb, W1b, b1, W2b, b2, out);
}

// Round 2
// 275.525 us; speedup vs baseline: 1.1099x; 1.0334x over previous
//
#include <hip/hip_runtime.h>
#include <hip/hip_bf16.h>

#define N_NODES 100000
#define N_EDGES 1600000
#define IN_DIM 48
#define OUT_DIM 128
#define K1 144                 // 3*IN_DIM
#define NSEG (2 * N_NODES)     // 200000 segments (node x {mi,mo})
#define NMSG (2 * N_EDGES)     // 3.2M directed messages
#define NBIN 784               // coarse bins: bin = seg >> 8  (784*256 >= NSEG)
#define BINCAP 4608            // per-bin region capacity: mean 4082 + ~8 sigma
#define EPB 4096               // edges per binscat block (391 blocks)
#define BTHREADS 1024          // 16 waves/block -> ~24 waves/CU resident
#define EPT (EPB / BTHREADS)   // 4 edges per thread, register-cached
#define XROW 64                // padded xb row: 64 u16 = 128B = 1 cache line

typedef unsigned short u16;
typedef unsigned long long u64;
typedef __attribute__((ext_vector_type(8))) short short8;
typedef __attribute__((ext_vector_type(4))) float f32x4;
typedef __attribute__((ext_vector_type(4))) unsigned uint4v;

// round-to-nearest-even f32 -> bf16 bits
static __device__ __forceinline__ u16 f2bf(float f) {
  unsigned u = __float_as_uint(f);
  unsigned r = (u + 0x7fffu + ((u >> 16) & 1u)) >> 16;
  return (u16)r;
}
// fast tanh: 1 - 2/(e^{2x}+1)  (v_exp_f32 + v_rcp_f32, ~1e-6 abs error)
static __device__ __forceinline__ float ftanh(float x) {
  return 1.f - 2.f * __builtin_amdgcn_rcpf(__expf(2.f * x) + 1.f);
}

// ---------------------------------------------------------------------------
// Stage 0: dtype conversions (fp32 -> bf16)
// ---------------------------------------------------------------------------
__global__ __launch_bounds__(256) void prep_w_kernel(
    const float* __restrict__ W1, const float* __restrict__ W2,
    u16* __restrict__ W1b, u16* __restrict__ W2b)
{
  int i = blockIdx.x * 256 + threadIdx.x;
  if (i < OUT_DIM * K1) {
    W1b[i] = f2bf(W1[i]);
  } else if (i < OUT_DIM * K1 + OUT_DIM * OUT_DIM) {
    int j = i - OUT_DIM * K1;
    W2b[j] = f2bf(W2[j]);
  }
}

// xb rows padded to 128B (XROW u16): dims 0..47 real, 48..63 zero.
__global__ __launch_bounds__(256) void prep_x_kernel(
    const float* __restrict__ x, u16* __restrict__ xb)
{
  int i = blockIdx.x * 256 + threadIdx.x;   // over N_NODES*XROW
  if (i < N_NODES * XROW) {
    int node = i >> 6;
    int d = i & 63;
    xb[i] = (d < IN_DIM) ? f2bf(x[node * IN_DIM + d]) : (u16)0;
  }
}

// ---------------------------------------------------------------------------
// Phase A: binscat — partition 3.2M messages into 784 coarse bins.
// Record (8B): .x = (seg_low << 24) | src, .y = fp32 w bits.
//   dir0 (mi): dst=col, src=row    dir1 (mo): dst=row, src=col
// 1024 threads/block (16 waves) for latency hiding; edges register-cached
// across the two passes (single global read of eidx/ea).
// Note (row*2+1)>>8 == row>>7 and (col*2)>>8 == col>>7: both directions of
// an edge bin by node>>7.
// ---------------------------------------------------------------------------
__global__ __launch_bounds__(BTHREADS) void binscat_kernel(
    const int* __restrict__ eidx, const float* __restrict__ ea,
    int* __restrict__ bin_cursor, int2* __restrict__ bkt)
{
  __shared__ int hist[NBIN];   // pass1: counts; then: within-bin write cursor
  for (int i = threadIdx.x; i < NBIN; i += BTHREADS) hist[i] = 0;
  __syncthreads();

  const int e0 = blockIdx.x * EPB;
  int rows[EPT], cols[EPT], ws[EPT];

#pragma unroll
  for (int u = 0; u < EPT; ++u) {
    int e = e0 + u * BTHREADS + threadIdx.x;
    rows[u] = -1;
    if (e < N_EDGES) {
      rows[u] = eidx[e];
      cols[u] = eidx[N_EDGES + e];
      ws[u]   = __float_as_int(ea[e]);
      atomicAdd(&hist[cols[u] >> 7], 1);
      atomicAdd(&hist[rows[u] >> 7], 1);
    }
  }
  __syncthreads();

  for (int b = threadIdx.x; b < NBIN; b += BTHREADS) {
    int c = hist[b];
    hist[b] = c ? atomicAdd(&bin_cursor[b], c) : 0;
  }
  __syncthreads();

#pragma unroll
  for (int u = 0; u < EPT; ++u) {
    if (rows[u] >= 0) {
      int row = rows[u], col = cols[u], w = ws[u];
      int seg0 = col * 2;
      int seg1 = row * 2 + 1;
      int s0 = atomicAdd(&hist[seg0 >> 8], 1);
      if (s0 < BINCAP)
        bkt[(size_t)(seg0 >> 8) * BINCAP + s0] =
            make_int2(((seg0 & 255) << 24) | row, w);
      int s1 = atomicAdd(&hist[seg1 >> 8], 1);
      if (s1 < BINCAP)
        bkt[(size_t)(seg1 >> 8) * BINCAP + s1] =
            make_int2(((seg1 & 255) << 24) | col, w);
    }
  }
}

// ---------------------------------------------------------------------------
// binscan: 1-block exclusive scan of the 784 bin counts -> bin_base
// ---------------------------------------------------------------------------
__global__ __launch_bounds__(256) void binscan_kernel(
    const int* __restrict__ bin_cursor, int* __restrict__ bin_base)
{
  __shared__ int sh[256];
  int carry = 0;
  for (int base = 0; base < NBIN; base += 256) {
    int idx = base + threadIdx.x;
    int v = (idx < NBIN) ? min(bin_cursor[idx], BINCAP) : 0;
    sh[threadIdx.x] = v;
    __syncthreads();
#pragma unroll
    for (int off = 1; off < 256; off <<= 1) {
      int t = (threadIdx.x >= off) ? sh[threadIdx.x - off] : 0;
      __syncthreads();
      sh[threadIdx.x] += t;
      __syncthreads();
    }
    if (idx < NBIN) bin_base[idx] = carry + (threadIdx.x ? sh[threadIdx.x - 1] : 0);
    carry += sh[255];
    __syncthreads();
  }
}

// ---------------------------------------------------------------------------
// Phase B: binsort — one block per bin. LDS hist over the bin's 256 segments,
// LDS scan, write exact per-segment offsets + 4B-packed CSR
// (rec = src<<15 | w_bf16_lo15; ea >= 0 so the bf16 sign bit is always 0).
// ---------------------------------------------------------------------------
__global__ __launch_bounds__(256) void binsort_kernel(
    const int2* __restrict__ bkt, const int* __restrict__ bin_cursor,
    const int* __restrict__ bin_base, unsigned* __restrict__ csr,
    int* __restrict__ offsets)
{
  __shared__ int hist[256];
  __shared__ int sh[256];
  const int b = blockIdx.x;
  const int cnt = min(bin_cursor[b], BINCAP);
  const int2* recs = bkt + (size_t)b * BINCAP;
  const int t = threadIdx.x;

  hist[t] = 0;
  __syncthreads();
  for (int j = t; j < cnt; j += 256)
    atomicAdd(&hist[(unsigned)recs[j].x >> 24], 1);
  __syncthreads();

  sh[t] = hist[t];
  __syncthreads();
#pragma unroll
  for (int off = 1; off < 256; off <<= 1) {
    int v = (t >= off) ? sh[t - off] : 0;
    __syncthreads();
    sh[t] += v;
    __syncthreads();
  }
  const int base = bin_base[b];
  const int excl = base + (t ? sh[t - 1] : 0);
  offsets[b * 256 + t] = excl;
  hist[t] = excl;
  __syncthreads();

  for (int j = t; j < cnt; j += 256) {
    int2 r = recs[j];
    int segl = (unsigned)r.x >> 24;
    unsigned src = (unsigned)r.x & 0xFFFFFFu;
    unsigned wb = f2bf(__int_as_float(r.y));
    int slot = atomicAdd(&hist[segl], 1);
    csr[slot] = (src << 15) | (wb & 0x7FFFu);
  }
}

// ---------------------------------------------------------------------------
// Gather: 8 segments per wave, 8 lanes per segment.
// Lane r8 owns dims [8*r8, 8*r8+8): one aligned dwordx4 (=1 cache line per
// record across the group). Uniform predicated loop to the wave-max segment
// length; inactive slots clamp to csr[0] (valid, finite) with w=0.
// No cross-lane reduce: each group's registers are its output row.
// Mseg layout: [node][0..47]=mi, [48..95]=mo (bf16) — unchanged.
// ---------------------------------------------------------------------------
__global__ __launch_bounds__(256) void gather_kernel(
    const unsigned* __restrict__ csr, const int* __restrict__ offs,
    const uint4v* __restrict__ xb4, u16* __restrict__ Mseg)
{
  const int lane = threadIdx.x & 63;
  const int g    = lane >> 3;                       // segment group 0..7
  const int r8   = lane & 7;                        // dim block within row
  const int seg  = blockIdx.x * 32 + (threadIdx.x >> 6) * 8 + g;

  const int beg = offs[seg];
  const int n   = offs[seg + 1] - beg;

  // wave-max of n (n is uniform within each 8-lane group -> 3 xor steps)
  int kmax = n;
  kmax = max(kmax, __shfl_xor(kmax, 8, 64));
  kmax = max(kmax, __shfl_xor(kmax, 16, 64));
  kmax = max(kmax, __shfl_xor(kmax, 32, 64));

  float a[8];
#pragma unroll
  for (int c = 0; c < 8; ++c) a[c] = 0.f;

  for (int it = 0; it < kmax; it += 2) {
    const bool p = (it     < n);
    const bool q = (it + 1 < n);
    unsigned rp = csr[p ? beg + it     : 0];
    unsigned rq = csr[q ? beg + it + 1 : 0];
    float wp = p ? __uint_as_float((rp & 0x7FFFu) << 16) : 0.f;
    float wq = q ? __uint_as_float((rq & 0x7FFFu) << 16) : 0.f;
    uint4v vp = xb4[(rp >> 15) * 8 + r8];
    uint4v vq = xb4[(rq >> 15) * 8 + r8];
#pragma unroll
    for (int c = 0; c < 4; ++c) {
      a[2 * c]     = fmaf(__uint_as_float(vp[c] << 16),         wp, a[2 * c]);
      a[2 * c + 1] = fmaf(__uint_as_float(vp[c] & 0xFFFF0000u), wp, a[2 * c + 1]);
    }
#pragma unroll
    for (int c = 0; c < 4; ++c) {
      a[2 * c]     = fmaf(__uint_as_float(vq[c] << 16),         wq, a[2 * c]);
      a[2 * c + 1] = fmaf(__uint_as_float(vq[c] & 0xFFFF0000u), wq, a[2 * c + 1]);
    }
  }

  if (r8 < 6) {                                     // dims 48..63 are pad
    unsigned d[4];
#pragma unroll
    for (int c = 0; c < 4; ++c)
      d[c] = (unsigned)f2bf(a[2 * c]) | ((unsigned)f2bf(a[2 * c + 1]) << 16);
    uint4v o = {d[0], d[1], d[2], d[3]};
    *(uint4v*)(Mseg + (size_t)seg * IN_DIM + r8 * 8) = o;
  }
}

// ---------------------------------------------------------------------------
// Stage 2: fused 2-layer MLP with MFMA 16x16x32 bf16.
// ---------------------------------------------------------------------------
static __device__ __forceinline__ short8 loadM(
    const u16* __restrict__ Mseg, const u16* __restrict__ xb, int m, int k)
{
  short8 r = {0, 0, 0, 0, 0, 0, 0, 0};
  if (k < 96) {
    r = *(const short8*)(Mseg + m * 96 + k);
  } else if (k < K1) {
    r = *(const short8*)(xb + m * XROW + (k - 96));   // padded 128B rows
  }
  return r;
}

__global__ __launch_bounds__(256) void mlp_kernel(
    const u16* __restrict__ Mseg, const u16* __restrict__ xb,
    const u16* __restrict__ W1b, const float* __restrict__ b1,
    const u16* __restrict__ W2b, const float* __restrict__ b2,
    float* __restrict__ out)
{
  __shared__ __align__(16) u16 hbuf[4][32][136];
  const int wave = threadIdx.x >> 6;
  const int lane = threadIdx.x & 63;
  const int col  = lane & 15;
  const int quad = lane >> 4;
  const int kq   = quad * 8;
  const int nodeBase = (blockIdx.x * 4 + wave) * 32;

  const int ma0 = min(nodeBase + col,      N_NODES - 1);
  const int ma1 = min(nodeBase + 16 + col, N_NODES - 1);

  f32x4 acc[2][8];
#pragma unroll
  for (int mt = 0; mt < 2; ++mt)
#pragma unroll
    for (int nt = 0; nt < 8; ++nt) acc[mt][nt] = (f32x4){0.f, 0.f, 0.f, 0.f};

#pragma unroll
  for (int ks = 0; ks < 5; ++ks) {
    const int k = ks * 32 + kq;
    short8 a0 = loadM(Mseg, xb, ma0, k);
    short8 a1 = loadM(Mseg, xb, ma1, k);
#pragma unroll
    for (int nt = 0; nt < 8; ++nt) {
      short8 b = {0, 0, 0, 0, 0, 0, 0, 0};
      if (k < K1)
        b = *(const short8*)(W1b + (nt * 16 + col) * K1 + k);
      acc[0][nt] = __builtin_amdgcn_mfma_f32_16x16x32_bf16(a0, b, acc[0][nt], 0, 0, 0);
      acc[1][nt] = __builtin_amdgcn_mfma_f32_16x16x32_bf16(a1, b, acc[1][nt], 0, 0, 0);
    }
  }

#pragma unroll
  for (int mt = 0; mt < 2; ++mt)
#pragma unroll
    for (int nt = 0; nt < 8; ++nt) {
      const int n = nt * 16 + col;
      const float bb = b1[n];
#pragma unroll
      for (int rg = 0; rg < 4; ++rg) {
        const int rowl = mt * 16 + quad * 4 + rg;
        hbuf[wave][rowl][n] = f2bf(ftanh(acc[mt][nt][rg] + bb));
      }
    }
  __syncthreads();

  f32x4 acc2[2][8];
#pragma unroll
  for (int mt = 0; mt < 2; ++mt)
#pragma unroll
    for (int nt = 0; nt < 8; ++nt) acc2[mt][nt] = (f32x4){0.f, 0.f, 0.f, 0.f};

#pragma unroll
  for (int ks = 0; ks < 4; ++ks) {
    const int k = ks * 32 + kq;
    short8 a0 = *(const short8*)&hbuf[wave][col][k];
    short8 a1 = *(const short8*)&hbuf[wave][16 + col][k];
#pragma unroll
    for (int nt = 0; nt < 8; ++nt) {
      short8 b = *(const short8*)(W2b + (nt * 16 + col) * OUT_DIM + k);
      acc2[0][nt] = __builtin_amdgcn_mfma_f32_16x16x32_bf16(a0, b, acc2[0][nt], 0, 0, 0);
      acc2[1][nt] = __builtin_amdgcn_mfma_f32_16x16x32_bf16(a1, b, acc2[1][nt], 0, 0, 0);
    }
  }

#pragma unroll
  for (int mt = 0; mt < 2; ++mt)
#pragma unroll
    for (int nt = 0; nt < 8; ++nt) {
      const int n = nt * 16 + col;
      const float bb = b2[n];
#pragma unroll
      for (int rg = 0; rg < 4; ++rg) {
        const int node = nodeBase + mt * 16 + quad * 4 + rg;
        if (node < N_NODES)
          out[node * OUT_DIM + n] = ftanh(acc2[mt][nt][rg] + bb);
      }
    }
}

extern "C" void kernel_launch(void* const* d_in, const int* in_sizes, int n_in,
                              void* d_out, int out_size, void* d_ws, size_t ws_size,
                              hipStream_t stream) {
  const float* x   = (const float*)d_in[0];
  const int* eidx  = (const int*)d_in[1];
  const float* ea  = (const float*)d_in[2];
  const float* W1  = (const float*)d_in[3];
  const float* b1  = (const float*)d_in[4];
  const float* W2  = (const float*)d_in[5];
  const float* b2  = (const float*)d_in[6];
  float* out = (float*)d_out;

  // workspace layout (16B-aligned), ~74.6 MB total:
  char* p = (char*)d_ws;
  u16* Mseg       = (u16*)p;      p += (size_t)NSEG * IN_DIM * 2;      // 19.2 MB
  u16* xb         = (u16*)p;      p += (size_t)N_NODES * XROW * 2;     // 12.8 MB (padded rows)
  u16* W1b        = (u16*)p;      p += OUT_DIM * K1 * 2;
  u16* W2b        = (u16*)p;      p += OUT_DIM * OUT_DIM * 2;
  int* bin_cursor = (int*)p;      p += 1024 * 4;
  int* bin_base   = (int*)p;      p += 1024 * 4;
  int* offsets    = (int*)p;      p += (size_t)(NBIN * 256 + 16) * 4;  //  0.8 MB
  int2* bkt       = (int2*)p;     p += (size_t)NBIN * BINCAP * 8;      // 28.9 MB
  unsigned* csr   = (unsigned*)p; p += (size_t)NMSG * 4;               // 12.8 MB

  hipMemsetAsync(bin_cursor, 0, 1024 * 4, stream);

  int prep_elems = OUT_DIM * K1 + OUT_DIM * OUT_DIM;
  prep_w_kernel<<<(prep_elems + 255) / 256, 256, 0, stream>>>(W1, W2, W1b, W2b);
  prep_x_kernel<<<(N_NODES * XROW + 255) / 256, 256, 0, stream>>>(x, xb);

  binscat_kernel<<<(N_EDGES + EPB - 1) / EPB, BTHREADS, 0, stream>>>(
      eidx, ea, bin_cursor, bkt);
  binscan_kernel<<<1, 256, 0, stream>>>(bin_cursor, bin_base);
  binsort_kernel<<<NBIN, 256, 0, stream>>>(bkt, bin_cursor, bin_base, csr, offsets);

  gather_kernel<<<NSEG / 32, 256, 0, stream>>>(
      csr, offsets, (const uint4v*)xb, Mseg);

  int nblocks = (N_NODES + 127) / 128;
  mlp_kernel<<<nblocks, 256, 0, stream>>>(Mseg, xb, W1b, b1, W2b, b2, out);
}

// Round 3
// 266.933 us; speedup vs baseline: 1.1456x; 1.0322x over previous
//
#include <hip/hip_runtime.h>
#include <hip/hip_bf16.h>

#define N_NODES 100000
#define N_EDGES 1600000
#define IN_DIM 48
#define OUT_DIM 128
#define K1 144                 // 3*IN_DIM
#define NSEG (2 * N_NODES)     // 200000 segments (node x {mi,mo})
#define NMSG (2 * N_EDGES)     // 3.2M directed messages
#define NBIN 784               // coarse bins: bin = seg >> 8  (784*256 >= NSEG)
#define BINCAP 4608            // per-bin region capacity: mean 4082 + ~8 sigma
#define EPB 4096               // edges per binscat block (391 blocks)
#define BTHREADS 1024          // 16 waves/block -> latency hiding in binscat
#define EPT (EPB / BTHREADS)   // 4 edges per thread, register-cached
#define XROW 64                // padded xb row: 64 u16 = 128B = 1 cache line
#define NTILE (N_NODES / 16)   // 6250 M-tiles of 16 nodes (exact)

typedef unsigned short u16;
typedef unsigned long long u64;
typedef __attribute__((ext_vector_type(8))) short short8;
typedef __attribute__((ext_vector_type(4))) float f32x4;
typedef __attribute__((ext_vector_type(4))) unsigned uint4v;

// round-to-nearest-even f32 -> bf16 bits
static __device__ __forceinline__ u16 f2bf(float f) {
  unsigned u = __float_as_uint(f);
  unsigned r = (u + 0x7fffu + ((u >> 16) & 1u)) >> 16;
  return (u16)r;
}
// fast tanh: 1 - 2/(e^{2x}+1)  (v_exp_f32 + v_rcp_f32, ~1e-6 abs error)
static __device__ __forceinline__ float ftanh(float x) {
  return 1.f - 2.f * __builtin_amdgcn_rcpf(__expf(2.f * x) + 1.f);
}

// ---------------------------------------------------------------------------
// Fragment layouts (MFMA 16x16x32 bf16, A-frag: lane l holds row (l&15),
// k-slice (l>>4)*8..+8):
//   Mf  [tile][ks(5)][lane(64)][8]   tile = node/16, k = ks*32+(l>>4)*8+j
//        k<48: mi, 48..95: mo, 96..143: x, 144..159: zero pad
//   W1f [nt(8)][ks(5)][lane(64)][8]  row nt*16+(l&15), zeros for k>=144
//   W2f [nt(8)][ks(4)][lane(64)][8]
// Every MFMA operand load is one contiguous 1KB wave transaction.
// ---------------------------------------------------------------------------

// Stage 0a: weights -> fragment order
__global__ __launch_bounds__(256) void prep_w_kernel(
    const float* __restrict__ W1, const float* __restrict__ W2,
    u16* __restrict__ W1f, u16* __restrict__ W2f)
{
  int i = blockIdx.x * 256 + threadIdx.x;
  if (i < 2560) {                       // 8 nt * 5 ks * 64 lanes
    int nt = i / 320;
    int r  = i - nt * 320;
    int ks = r >> 6, l = r & 63;
    int nrow = nt * 16 + (l & 15);
    int k0 = ks * 32 + (l >> 4) * 8;
#pragma unroll
    for (int j = 0; j < 8; ++j) {
      int k = k0 + j;
      W1f[(size_t)i * 8 + j] = (k < K1) ? f2bf(W1[nrow * K1 + k]) : (u16)0;
    }
  } else if (i < 2560 + 2048) {         // 8 nt * 4 ks * 64 lanes
    int i2 = i - 2560;
    int nt = i2 >> 8;
    int r  = i2 & 255;
    int ks = r >> 6, l = r & 63;
    int nrow = nt * 16 + (l & 15);
    int k0 = ks * 32 + (l >> 4) * 8;
#pragma unroll
    for (int j = 0; j < 8; ++j)
      W2f[(size_t)i2 * 8 + j] = f2bf(W2[nrow * OUT_DIM + k0 + j]);
  }
}

// Stage 0b: x -> padded xb rows (gather source) + Mf x-part (k in [96,160)).
// NOTE: Mf aliases bkt, so this runs AFTER binsort in the stream.
__global__ __launch_bounds__(256) void prep_x_kernel(
    const float* __restrict__ x, u16* __restrict__ xb, u16* __restrict__ Mf)
{
  int i = blockIdx.x * 256 + threadIdx.x;   // over N_NODES*64 (exact grid)
  int node = i >> 6;
  int d = i & 63;
  u16 v = (d < IN_DIM) ? f2bf(x[node * IN_DIM + d]) : (u16)0;
  xb[i] = v;
  int k = 96 + d;                           // 96..159 (>=144 -> zero pad)
  int tile = node >> 4, c = node & 15;
  int ks = k >> 5, q = (k >> 3) & 3, j = k & 7;
  Mf[((size_t)(tile * 5 + ks) * 64 + q * 16 + c) * 8 + j] = v;
}

// ---------------------------------------------------------------------------
// Phase A: binscat — partition 3.2M messages into 784 coarse bins.
// Record (8B): .x = (seg_low << 24) | src, .y = fp32 w bits.
//   dir0 (mi): dst=col, src=row    dir1 (mo): dst=row, src=col
// ---------------------------------------------------------------------------
__global__ __launch_bounds__(BTHREADS) void binscat_kernel(
    const int* __restrict__ eidx, const float* __restrict__ ea,
    int* __restrict__ bin_cursor, int2* __restrict__ bkt)
{
  __shared__ int hist[NBIN];   // pass1: counts; then: within-bin write cursor
  for (int i = threadIdx.x; i < NBIN; i += BTHREADS) hist[i] = 0;
  __syncthreads();

  const int e0 = blockIdx.x * EPB;
  int rows[EPT], cols[EPT], ws[EPT];

#pragma unroll
  for (int u = 0; u < EPT; ++u) {
    int e = e0 + u * BTHREADS + threadIdx.x;
    rows[u] = -1;
    if (e < N_EDGES) {
      rows[u] = eidx[e];
      cols[u] = eidx[N_EDGES + e];
      ws[u]   = __float_as_int(ea[e]);
      atomicAdd(&hist[cols[u] >> 7], 1);
      atomicAdd(&hist[rows[u] >> 7], 1);
    }
  }
  __syncthreads();

  for (int b = threadIdx.x; b < NBIN; b += BTHREADS) {
    int c = hist[b];
    hist[b] = c ? atomicAdd(&bin_cursor[b], c) : 0;
  }
  __syncthreads();

#pragma unroll
  for (int u = 0; u < EPT; ++u) {
    if (rows[u] >= 0) {
      int row = rows[u], col = cols[u], w = ws[u];
      int seg0 = col * 2;
      int seg1 = row * 2 + 1;
      int s0 = atomicAdd(&hist[seg0 >> 8], 1);
      if (s0 < BINCAP)
        bkt[(size_t)(seg0 >> 8) * BINCAP + s0] =
            make_int2(((seg0 & 255) << 24) | row, w);
      int s1 = atomicAdd(&hist[seg1 >> 8], 1);
      if (s1 < BINCAP)
        bkt[(size_t)(seg1 >> 8) * BINCAP + s1] =
            make_int2(((seg1 & 255) << 24) | col, w);
    }
  }
}

// ---------------------------------------------------------------------------
// binscan: 1-block exclusive scan of the 784 bin counts -> bin_base
// ---------------------------------------------------------------------------
__global__ __launch_bounds__(256) void binscan_kernel(
    const int* __restrict__ bin_cursor, int* __restrict__ bin_base)
{
  __shared__ int sh[256];
  int carry = 0;
  for (int base = 0; base < NBIN; base += 256) {
    int idx = base + threadIdx.x;
    int v = (idx < NBIN) ? min(bin_cursor[idx], BINCAP) : 0;
    sh[threadIdx.x] = v;
    __syncthreads();
#pragma unroll
    for (int off = 1; off < 256; off <<= 1) {
      int t = (threadIdx.x >= off) ? sh[threadIdx.x - off] : 0;
      __syncthreads();
      sh[threadIdx.x] += t;
      __syncthreads();
    }
    if (idx < NBIN) bin_base[idx] = carry + (threadIdx.x ? sh[threadIdx.x - 1] : 0);
    carry += sh[255];
    __syncthreads();
  }
}

// ---------------------------------------------------------------------------
// Phase B: binsort — one block per bin. LDS hist over the bin's 256 segments,
// LDS scan, write exact per-segment offsets + 4B-packed CSR
// (rec = src<<15 | w_bf16_lo15; ea >= 0 so the bf16 sign bit is always 0).
// ---------------------------------------------------------------------------
__global__ __launch_bounds__(256) void binsort_kernel(
    const int2* __restrict__ bkt, const int* __restrict__ bin_cursor,
    const int* __restrict__ bin_base, unsigned* __restrict__ csr,
    int* __restrict__ offsets)
{
  __shared__ int hist[256];
  __shared__ int sh[256];
  const int b = blockIdx.x;
  const int cnt = min(bin_cursor[b], BINCAP);
  const int2* recs = bkt + (size_t)b * BINCAP;
  const int t = threadIdx.x;

  hist[t] = 0;
  __syncthreads();
  for (int j = t; j < cnt; j += 256)
    atomicAdd(&hist[(unsigned)recs[j].x >> 24], 1);
  __syncthreads();

  sh[t] = hist[t];
  __syncthreads();
#pragma unroll
  for (int off = 1; off < 256; off <<= 1) {
    int v = (t >= off) ? sh[t - off] : 0;
    __syncthreads();
    sh[t] += v;
    __syncthreads();
  }
  const int base = bin_base[b];
  const int excl = base + (t ? sh[t - 1] : 0);
  offsets[b * 256 + t] = excl;
  hist[t] = excl;
  __syncthreads();

  for (int j = t; j < cnt; j += 256) {
    int2 r = recs[j];
    int segl = (unsigned)r.x >> 24;
    unsigned src = (unsigned)r.x & 0xFFFFFFu;
    unsigned wb = f2bf(__int_as_float(r.y));
    int slot = atomicAdd(&hist[segl], 1);
    csr[slot] = (src << 15) | (wb & 0x7FFFu);
  }
}

// ---------------------------------------------------------------------------
// Gather: 8 segments per wave, 8 lanes per segment; writes A-fragment-order Mf.
// Lane r8 owns dims [8*r8, 8*r8+8): one aligned dwordx4 per record.
// ---------------------------------------------------------------------------
__global__ __launch_bounds__(256) void gather_kernel(
    const unsigned* __restrict__ csr, const int* __restrict__ offs,
    const uint4v* __restrict__ xb4, u16* __restrict__ Mf)
{
  const int lane = threadIdx.x & 63;
  const int g    = lane >> 3;                       // segment group 0..7
  const int r8   = lane & 7;                        // dim block within row
  const int seg  = blockIdx.x * 32 + (threadIdx.x >> 6) * 8 + g;

  const int beg = offs[seg];
  const int n   = offs[seg + 1] - beg;

  // wave-max of n (n is uniform within each 8-lane group -> 3 xor steps)
  int kmax = n;
  kmax = max(kmax, __shfl_xor(kmax, 8, 64));
  kmax = max(kmax, __shfl_xor(kmax, 16, 64));
  kmax = max(kmax, __shfl_xor(kmax, 32, 64));

  float a[8];
#pragma unroll
  for (int c = 0; c < 8; ++c) a[c] = 0.f;

  for (int it = 0; it < kmax; it += 2) {
    const bool p = (it     < n);
    const bool q = (it + 1 < n);
    unsigned rp = csr[p ? beg + it     : 0];
    unsigned rq = csr[q ? beg + it + 1 : 0];
    float wp = p ? __uint_as_float((rp & 0x7FFFu) << 16) : 0.f;
    float wq = q ? __uint_as_float((rq & 0x7FFFu) << 16) : 0.f;
    uint4v vp = xb4[(rp >> 15) * 8 + r8];
    uint4v vq = xb4[(rq >> 15) * 8 + r8];
#pragma unroll
    for (int c = 0; c < 4; ++c) {
      a[2 * c]     = fmaf(__uint_as_float(vp[c] << 16),         wp, a[2 * c]);
      a[2 * c + 1] = fmaf(__uint_as_float(vp[c] & 0xFFFF0000u), wp, a[2 * c + 1]);
    }
#pragma unroll
    for (int c = 0; c < 4; ++c) {
      a[2 * c]     = fmaf(__uint_as_float(vq[c] << 16),         wq, a[2 * c]);
      a[2 * c + 1] = fmaf(__uint_as_float(vq[c] & 0xFFFF0000u), wq, a[2 * c + 1]);
    }
  }

  if (r8 < 6) {                                     // dims >=48 don't exist
    unsigned d[4];
#pragma unroll
    for (int c = 0; c < 4; ++c)
      d[c] = (unsigned)f2bf(a[2 * c]) | ((unsigned)f2bf(a[2 * c + 1]) << 16);
    uint4v o = {d[0], d[1], d[2], d[3]};
    const int node = seg >> 1;
    const int k0 = (seg & 1) * 48 + r8 * 8;         // 8-aligned, one frag
    const int ks = k0 >> 5, q = (k0 >> 3) & 3;
    *(uint4v*)(Mf + ((size_t)((seg >> 5) * 5 + ks) * 64 + q * 16 + (node & 15)) * 8) = o;
  }
}

// ---------------------------------------------------------------------------
// Stage 2: fused 2-layer MLP. M=16 nodes/wave, all operand loads are
// contiguous 1KB fragment loads. 6250 waves -> ~24 resident/CU.
// ---------------------------------------------------------------------------
__global__ __launch_bounds__(256, 6) void mlp_kernel(
    const u16* __restrict__ Mf, const u16* __restrict__ W1f,
    const float* __restrict__ b1, const u16* __restrict__ W2f,
    const float* __restrict__ b2, float* __restrict__ out)
{
  __shared__ __align__(16) u16 hbuf[4][16][136];
  const int wave = threadIdx.x >> 6;
  const int lane = threadIdx.x & 63;
  const int col  = lane & 15;
  const int quad = lane >> 4;
  const int tile0 = blockIdx.x * 4 + wave;
  const bool active = tile0 < NTILE;
  const int tile = active ? tile0 : NTILE - 1;

  f32x4 acc[8];
#pragma unroll
  for (int nt = 0; nt < 8; ++nt) acc[nt] = (f32x4){0.f, 0.f, 0.f, 0.f};

#pragma unroll
  for (int ks = 0; ks < 5; ++ks) {
    short8 a = *(const short8*)(Mf + ((size_t)tile * 5 + ks) * 512 + lane * 8);
#pragma unroll
    for (int nt = 0; nt < 8; ++nt) {
      short8 b = *(const short8*)(W1f + ((nt * 5 + ks) * 64 + lane) * 8);
      acc[nt] = __builtin_amdgcn_mfma_f32_16x16x32_bf16(a, b, acc[nt], 0, 0, 0);
    }
  }

#pragma unroll
  for (int nt = 0; nt < 8; ++nt) {
    const int n = nt * 16 + col;
    const float bb = b1[n];
#pragma unroll
    for (int rg = 0; rg < 4; ++rg)
      hbuf[wave][quad * 4 + rg][n] = f2bf(ftanh(acc[nt][rg] + bb));
  }
  __syncthreads();

  f32x4 acc2[8];
#pragma unroll
  for (int nt = 0; nt < 8; ++nt) acc2[nt] = (f32x4){0.f, 0.f, 0.f, 0.f};

#pragma unroll
  for (int ks = 0; ks < 4; ++ks) {
    short8 a = *(const short8*)&hbuf[wave][col][quad * 8 + ks * 32];
#pragma unroll
    for (int nt = 0; nt < 8; ++nt) {
      short8 b = *(const short8*)(W2f + ((nt * 4 + ks) * 64 + lane) * 8);
      acc2[nt] = __builtin_amdgcn_mfma_f32_16x16x32_bf16(a, b, acc2[nt], 0, 0, 0);
    }
  }

  if (active) {
#pragma unroll
    for (int nt = 0; nt < 8; ++nt) {
      const int n = nt * 16 + col;
      const float bb = b2[n];
#pragma unroll
      for (int rg = 0; rg < 4; ++rg) {
        const int node = tile * 16 + quad * 4 + rg;
        out[(size_t)node * OUT_DIM + n] = ftanh(acc2[nt][rg] + bb);
      }
    }
  }
}

extern "C" void kernel_launch(void* const* d_in, const int* in_sizes, int n_in,
                              void* d_out, int out_size, void* d_ws, size_t ws_size,
                              hipStream_t stream) {
  const float* x   = (const float*)d_in[0];
  const int* eidx  = (const int*)d_in[1];
  const float* ea  = (const float*)d_in[2];
  const float* W1  = (const float*)d_in[3];
  const float* b1  = (const float*)d_in[4];
  const float* W2  = (const float*)d_in[5];
  const float* b2  = (const float*)d_in[6];
  float* out = (float*)d_out;

  // workspace layout (16B-aligned), ~58.5 MB total.
  // Mf (32 MB) ALIASES bkt (28.9 MB): bkt is dead after binsort, and all Mf
  // writers (prep_x, gather) run after binsort in the stream.
  char* p = (char*)d_ws;
  u16* Mf         = (u16*)p;
  int2* bkt       = (int2*)p;     p += (size_t)NTILE * 5 * 512 * 2;    // 32 MB
  u16* xb         = (u16*)p;      p += (size_t)N_NODES * XROW * 2;     // 12.8 MB
  u16* W1f        = (u16*)p;      p += (size_t)2560 * 8 * 2;           // 40 KB
  u16* W2f        = (u16*)p;      p += (size_t)2048 * 8 * 2;           // 32 KB
  int* bin_cursor = (int*)p;      p += 1024 * 4;
  int* bin_base   = (int*)p;      p += 1024 * 4;
  int* offsets    = (int*)p;      p += (size_t)(NBIN * 256 + 16) * 4;  //  0.8 MB
  unsigned* csr   = (unsigned*)p; p += (size_t)NMSG * 4;               // 12.8 MB

  hipMemsetAsync(bin_cursor, 0, 1024 * 4, stream);

  prep_w_kernel<<<(2560 + 2048 + 255) / 256, 256, 0, stream>>>(W1, W2, W1f, W2f);

  binscat_kernel<<<(N_EDGES + EPB - 1) / EPB, BTHREADS, 0, stream>>>(
      eidx, ea, bin_cursor, bkt);
  binscan_kernel<<<1, 256, 0, stream>>>(bin_cursor, bin_base);
  binsort_kernel<<<NBIN, 256, 0, stream>>>(bkt, bin_cursor, bin_base, csr, offsets);

  // after binsort: bkt dead -> Mf region free to write
  prep_x_kernel<<<(N_NODES * XROW) / 256, 256, 0, stream>>>(x, xb, Mf);
  gather_kernel<<<NSEG / 32, 256, 0, stream>>>(
      csr, offsets, (const uint4v*)xb, Mf);

  mlp_kernel<<<(NTILE + 3) / 4, 256, 0, stream>>>(Mf, W1f, b1, W2f, b2, out);
}

// Round 4
// 240.708 us; speedup vs baseline: 1.2704x; 1.1089x over previous
//
#include <hip/hip_runtime.h>
#include <hip/hip_bf16.h>

#define N_NODES 100000
#define N_EDGES 1600000
#define IN_DIM 48
#define OUT_DIM 128
#define K1 144                 // 3*IN_DIM
#define NSEG (2 * N_NODES)     // 200000 segments (node x {mi,mo})
#define NMSG (2 * N_EDGES)     // 3.2M directed messages
#define NBIN 784               // coarse bins: bin = seg >> 8  (784*256 >= NSEG)
#define BINCAP 4608            // per-bin region capacity: mean 4082 + ~8 sigma
#define EPB 4096               // edges per binscat block (391 blocks)
#define BTHREADS 1024          // 16 waves/block -> latency hiding in binscat
#define EPT (EPB / BTHREADS)   // 4 edges per thread, register-cached
#define XROW 64                // padded xb row: 64 u16 = 128B = 1 cache line
#define NTILE (N_NODES / 16)   // 6250 tiles of 16 nodes (exact)

typedef unsigned short u16;
typedef unsigned long long u64;
typedef __attribute__((ext_vector_type(8))) short short8;
typedef __attribute__((ext_vector_type(4))) float f32x4;
typedef __attribute__((ext_vector_type(4))) unsigned uint4v;

// round-to-nearest-even f32 -> bf16 bits
static __device__ __forceinline__ u16 f2bf(float f) {
  unsigned u = __float_as_uint(f);
  unsigned r = (u + 0x7fffu + ((u >> 16) & 1u)) >> 16;
  return (u16)r;
}
// fast tanh: 1 - 2/(e^{2x}+1)  (v_exp_f32 + v_rcp_f32, ~1e-6 abs error)
static __device__ __forceinline__ float ftanh(float x) {
  return 1.f - 2.f * __builtin_amdgcn_rcpf(__expf(2.f * x) + 1.f);
}

// ---------------------------------------------------------------------------
// Fragment layouts (MFMA 16x16x32 bf16, A-frag: lane l holds row (l&15),
// k-slice (l>>4)*8..+8):
//   W1f [nt(8)][ks(5)][lane(64)][8]  row nt*16+(l&15), zeros for k>=144
//   W2f [nt(8)][ks(4)][lane(64)][8]
// Per-block LDS M fragment: Msh[ks(5)][lane(64)][8] for the 16-node tile,
// k<48: mi, 48..95: mo, 96..143: x, 144..159: zero pad.
// ---------------------------------------------------------------------------

// Stage 0a: weights -> fragment order
__global__ __launch_bounds__(256) void prep_w_kernel(
    const float* __restrict__ W1, const float* __restrict__ W2,
    u16* __restrict__ W1f, u16* __restrict__ W2f)
{
  int i = blockIdx.x * 256 + threadIdx.x;
  if (i < 2560) {                       // 8 nt * 5 ks * 64 lanes
    int nt = i / 320;
    int r  = i - nt * 320;
    int ks = r >> 6, l = r & 63;
    int nrow = nt * 16 + (l & 15);
    int k0 = ks * 32 + (l >> 4) * 8;
#pragma unroll
    for (int j = 0; j < 8; ++j) {
      int k = k0 + j;
      W1f[(size_t)i * 8 + j] = (k < K1) ? f2bf(W1[nrow * K1 + k]) : (u16)0;
    }
  } else if (i < 2560 + 2048) {         // 8 nt * 4 ks * 64 lanes
    int i2 = i - 2560;
    int nt = i2 >> 8;
    int r  = i2 & 255;
    int ks = r >> 6, l = r & 63;
    int nrow = nt * 16 + (l & 15);
    int k0 = ks * 32 + (l >> 4) * 8;
#pragma unroll
    for (int j = 0; j < 8; ++j)
      W2f[(size_t)i2 * 8 + j] = f2bf(W2[nrow * OUT_DIM + k0 + j]);
  }
}

// Stage 0b: x -> padded xb rows (dims 48..63 zero -> doubles as the k>=144
// zero pad when tiles are loaded into Msh).
__global__ __launch_bounds__(256) void prep_x_kernel(
    const float* __restrict__ x, u16* __restrict__ xb)
{
  int i = blockIdx.x * 256 + threadIdx.x;   // over N_NODES*64 (exact grid)
  int node = i >> 6;
  int d = i & 63;
  xb[i] = (d < IN_DIM) ? f2bf(x[node * IN_DIM + d]) : (u16)0;
}

// ---------------------------------------------------------------------------
// Phase A: binscat — partition 3.2M messages into 784 coarse bins.
// Record (8B): .x = (seg_low << 24) | src, .y = fp32 w bits.
//   dir0 (mi): dst=col, src=row    dir1 (mo): dst=row, src=col
// ---------------------------------------------------------------------------
__global__ __launch_bounds__(BTHREADS) void binscat_kernel(
    const int* __restrict__ eidx, const float* __restrict__ ea,
    int* __restrict__ bin_cursor, int2* __restrict__ bkt)
{
  __shared__ int hist[NBIN];   // pass1: counts; then: within-bin write cursor
  for (int i = threadIdx.x; i < NBIN; i += BTHREADS) hist[i] = 0;
  __syncthreads();

  const int e0 = blockIdx.x * EPB;
  int rows[EPT], cols[EPT], ws[EPT];

#pragma unroll
  for (int u = 0; u < EPT; ++u) {
    int e = e0 + u * BTHREADS + threadIdx.x;
    rows[u] = -1;
    if (e < N_EDGES) {
      rows[u] = eidx[e];
      cols[u] = eidx[N_EDGES + e];
      ws[u]   = __float_as_int(ea[e]);
      atomicAdd(&hist[cols[u] >> 7], 1);
      atomicAdd(&hist[rows[u] >> 7], 1);
    }
  }
  __syncthreads();

  for (int b = threadIdx.x; b < NBIN; b += BTHREADS) {
    int c = hist[b];
    hist[b] = c ? atomicAdd(&bin_cursor[b], c) : 0;
  }
  __syncthreads();

#pragma unroll
  for (int u = 0; u < EPT; ++u) {
    if (rows[u] >= 0) {
      int row = rows[u], col = cols[u], w = ws[u];
      int seg0 = col * 2;
      int seg1 = row * 2 + 1;
      int s0 = atomicAdd(&hist[seg0 >> 8], 1);
      if (s0 < BINCAP)
        bkt[(size_t)(seg0 >> 8) * BINCAP + s0] =
            make_int2(((seg0 & 255) << 24) | row, w);
      int s1 = atomicAdd(&hist[seg1 >> 8], 1);
      if (s1 < BINCAP)
        bkt[(size_t)(seg1 >> 8) * BINCAP + s1] =
            make_int2(((seg1 & 255) << 24) | col, w);
    }
  }
}

// ---------------------------------------------------------------------------
// binscan: 1-block exclusive scan of the 784 bin counts -> bin_base
// ---------------------------------------------------------------------------
__global__ __launch_bounds__(256) void binscan_kernel(
    const int* __restrict__ bin_cursor, int* __restrict__ bin_base)
{
  __shared__ int sh[256];
  int carry = 0;
  for (int base = 0; base < NBIN; base += 256) {
    int idx = base + threadIdx.x;
    int v = (idx < NBIN) ? min(bin_cursor[idx], BINCAP) : 0;
    sh[threadIdx.x] = v;
    __syncthreads();
#pragma unroll
    for (int off = 1; off < 256; off <<= 1) {
      int t = (threadIdx.x >= off) ? sh[threadIdx.x - off] : 0;
      __syncthreads();
      sh[threadIdx.x] += t;
      __syncthreads();
    }
    if (idx < NBIN) bin_base[idx] = carry + (threadIdx.x ? sh[threadIdx.x - 1] : 0);
    carry += sh[255];
    __syncthreads();
  }
}

// ---------------------------------------------------------------------------
// Phase B: binsort — one block per bin. LDS hist over the bin's 256 segments,
// LDS scan, write exact per-segment offsets + 4B-packed CSR
// (rec = src<<15 | w_bf16_lo15; ea >= 0 so the bf16 sign bit is always 0).
// ---------------------------------------------------------------------------
__global__ __launch_bounds__(256) void binsort_kernel(
    const int2* __restrict__ bkt, const int* __restrict__ bin_cursor,
    const int* __restrict__ bin_base, unsigned* __restrict__ csr,
    int* __restrict__ offsets)
{
  __shared__ int hist[256];
  __shared__ int sh[256];
  const int b = blockIdx.x;
  const int cnt = min(bin_cursor[b], BINCAP);
  const int2* recs = bkt + (size_t)b * BINCAP;
  const int t = threadIdx.x;

  hist[t] = 0;
  __syncthreads();
  for (int j = t; j < cnt; j += 256)
    atomicAdd(&hist[(unsigned)recs[j].x >> 24], 1);
  __syncthreads();

  sh[t] = hist[t];
  __syncthreads();
#pragma unroll
  for (int off = 1; off < 256; off <<= 1) {
    int v = (t >= off) ? sh[t - off] : 0;
    __syncthreads();
    sh[t] += v;
    __syncthreads();
  }
  const int base = bin_base[b];
  const int excl = base + (t ? sh[t - 1] : 0);
  offsets[b * 256 + t] = excl;
  hist[t] = excl;
  __syncthreads();

  for (int j = t; j < cnt; j += 256) {
    int2 r = recs[j];
    int segl = (unsigned)r.x >> 24;
    unsigned src = (unsigned)r.x & 0xFFFFFFu;
    unsigned wb = f2bf(__int_as_float(r.y));
    int slot = atomicAdd(&hist[segl], 1);
    csr[slot] = (src << 15) | (wb & 0x7FFFu);
  }
}

// ---------------------------------------------------------------------------
// Fused gather + 2-layer MLP. One block = 16 nodes = 32 segments.
// Phase 1: each wave gathers 8 segments (8 lanes/seg, lane r8 owns dims
//   [8*r8,8*r8+8), one aligned dwordx4 per record) -> Msh A-fragments in LDS.
//   Threads 0..127 also stage the 16 xb rows (contiguous 2KB) into the
//   k=96..159 fragment slots (xb's zero pad supplies k>=144 zeros).
// Phase 2: the 4 waves split the 8 N-tiles (2 each): layer1 MFMA from
//   Msh + W1f, tanh -> hsh, layer2 MFMA from hsh + W2f, tanh -> out.
// ---------------------------------------------------------------------------
__global__ __launch_bounds__(256, 4) void gmlp_kernel(
    const unsigned* __restrict__ csr, const int* __restrict__ offs,
    const uint4v* __restrict__ xb4, const u16* __restrict__ W1f,
    const float* __restrict__ b1, const u16* __restrict__ W2f,
    const float* __restrict__ b2, float* __restrict__ out)
{
  __shared__ __align__(16) u16 Msh[5 * 64 * 8];   // 5KB: [ks][lane][8]
  __shared__ __align__(16) u16 hsh[16][136];      // 4.25KB

  const int tile = blockIdx.x;
  const int tid  = threadIdx.x;
  const int wave = tid >> 6;
  const int lane = tid & 63;
  const int g    = lane >> 3;                     // segment group 0..7
  const int r8   = lane & 7;                      // dim block within row
  const int seg  = tile * 32 + wave * 8 + g;

  // ---- phase 1a: stage x rows into Msh (threads 0..127, contiguous loads)
  if (tid < 128) {
    const int nl  = tid >> 3;                     // node_local 0..15
    const int r8x = tid & 7;                      // k chunk 96+8*r8x
    uint4v v = xb4[(size_t)(tile * 16 + nl) * 8 + r8x];
    const int ks = 3 + (r8x >> 2);
    const int q  = r8x & 3;
    *(uint4v*)&Msh[((ks * 64) + q * 16 + nl) * 8] = v;
  }

  // ---- phase 1b: gather 8 segments/wave (loop identical to r3 gather)
  const int beg = offs[seg];
  const int n   = offs[seg + 1] - beg;

  int kmax = n;
  kmax = max(kmax, __shfl_xor(kmax, 8, 64));
  kmax = max(kmax, __shfl_xor(kmax, 16, 64));
  kmax = max(kmax, __shfl_xor(kmax, 32, 64));

  float a[8];
#pragma unroll
  for (int c = 0; c < 8; ++c) a[c] = 0.f;

  for (int it = 0; it < kmax; it += 2) {
    const bool p = (it     < n);
    const bool q = (it + 1 < n);
    unsigned rp = csr[p ? beg + it     : 0];
    unsigned rq = csr[q ? beg + it + 1 : 0];
    float wp = p ? __uint_as_float((rp & 0x7FFFu) << 16) : 0.f;
    float wq = q ? __uint_as_float((rq & 0x7FFFu) << 16) : 0.f;
    uint4v vp = xb4[(rp >> 15) * 8 + r8];
    uint4v vq = xb4[(rq >> 15) * 8 + r8];
#pragma unroll
    for (int c = 0; c < 4; ++c) {
      a[2 * c]     = fmaf(__uint_as_float(vp[c] << 16),         wp, a[2 * c]);
      a[2 * c + 1] = fmaf(__uint_as_float(vp[c] & 0xFFFF0000u), wp, a[2 * c + 1]);
    }
#pragma unroll
    for (int c = 0; c < 4; ++c) {
      a[2 * c]     = fmaf(__uint_as_float(vq[c] << 16),         wq, a[2 * c]);
      a[2 * c + 1] = fmaf(__uint_as_float(vq[c] & 0xFFFF0000u), wq, a[2 * c + 1]);
    }
  }

  if (r8 < 6) {                                   // dims >=48 don't exist
    unsigned d[4];
#pragma unroll
    for (int c = 0; c < 4; ++c)
      d[c] = (unsigned)f2bf(a[2 * c]) | ((unsigned)f2bf(a[2 * c + 1]) << 16);
    uint4v o = {d[0], d[1], d[2], d[3]};
    const int nl   = (wave * 8 + g) >> 1;         // node_local 0..15
    const int half = g & 1;                       // 0: mi, 1: mo
    const int k0   = half * 48 + r8 * 8;
    const int ks   = k0 >> 5;
    const int q    = (k0 >> 3) & 3;
    *(uint4v*)&Msh[((ks * 64) + q * 16 + nl) * 8] = o;
  }
  __syncthreads();

  // ---- phase 2: MLP, each wave handles nt = wave*2, wave*2+1
  const int col  = lane & 15;
  const int quad = lane >> 4;
  const int nt0  = wave * 2;

  f32x4 acc[2];
  acc[0] = (f32x4){0.f, 0.f, 0.f, 0.f};
  acc[1] = (f32x4){0.f, 0.f, 0.f, 0.f};

#pragma unroll
  for (int ks = 0; ks < 5; ++ks) {
    short8 afr = *(const short8*)&Msh[(ks * 64 + lane) * 8];
#pragma unroll
    for (int ntl = 0; ntl < 2; ++ntl) {
      const int nt = nt0 + ntl;
      short8 b = *(const short8*)(W1f + ((nt * 5 + ks) * 64 + lane) * 8);
      acc[ntl] = __builtin_amdgcn_mfma_f32_16x16x32_bf16(afr, b, acc[ntl], 0, 0, 0);
    }
  }

#pragma unroll
  for (int ntl = 0; ntl < 2; ++ntl) {
    const int nt = nt0 + ntl;
    const int nn = nt * 16 + col;
    const float bb = b1[nn];
#pragma unroll
    for (int rg = 0; rg < 4; ++rg)
      hsh[quad * 4 + rg][nn] = f2bf(ftanh(acc[ntl][rg] + bb));
  }
  __syncthreads();

  f32x4 acc2[2];
  acc2[0] = (f32x4){0.f, 0.f, 0.f, 0.f};
  acc2[1] = (f32x4){0.f, 0.f, 0.f, 0.f};

#pragma unroll
  for (int ks = 0; ks < 4; ++ks) {
    short8 afr = *(const short8*)&hsh[col][ks * 32 + quad * 8];
#pragma unroll
    for (int ntl = 0; ntl < 2; ++ntl) {
      const int nt = nt0 + ntl;
      short8 b = *(const short8*)(W2f + ((nt * 4 + ks) * 64 + lane) * 8);
      acc2[ntl] = __builtin_amdgcn_mfma_f32_16x16x32_bf16(afr, b, acc2[ntl], 0, 0, 0);
    }
  }

#pragma unroll
  for (int ntl = 0; ntl < 2; ++ntl) {
    const int nt = nt0 + ntl;
    const int nn = nt * 16 + col;
    const float bb = b2[nn];
#pragma unroll
    for (int rg = 0; rg < 4; ++rg) {
      const int node = tile * 16 + quad * 4 + rg;
      out[(size_t)node * OUT_DIM + nn] = ftanh(acc2[ntl][rg] + bb);
    }
  }
}

extern "C" void kernel_launch(void* const* d_in, const int* in_sizes, int n_in,
                              void* d_out, int out_size, void* d_ws, size_t ws_size,
                              hipStream_t stream) {
  const float* x   = (const float*)d_in[0];
  const int* eidx  = (const int*)d_in[1];
  const float* ea  = (const float*)d_in[2];
  const float* W1  = (const float*)d_in[3];
  const float* b1  = (const float*)d_in[4];
  const float* W2  = (const float*)d_in[5];
  const float* b2  = (const float*)d_in[6];
  float* out = (float*)d_out;

  // workspace layout (16B-aligned), ~55.3 MB total (Mf eliminated by fusion):
  char* p = (char*)d_ws;
  int2* bkt       = (int2*)p;     p += (size_t)NBIN * BINCAP * 8;      // 28.9 MB
  u16* xb         = (u16*)p;      p += (size_t)N_NODES * XROW * 2;     // 12.8 MB
  u16* W1f        = (u16*)p;      p += (size_t)2560 * 8 * 2;           // 40 KB
  u16* W2f        = (u16*)p;      p += (size_t)2048 * 8 * 2;           // 32 KB
  int* bin_cursor = (int*)p;      p += 1024 * 4;
  int* bin_base   = (int*)p;      p += 1024 * 4;
  int* offsets    = (int*)p;      p += (size_t)(NBIN * 256 + 16) * 4;  //  0.8 MB
  unsigned* csr   = (unsigned*)p; p += (size_t)NMSG * 4;               // 12.8 MB

  hipMemsetAsync(bin_cursor, 0, 1024 * 4, stream);

  prep_w_kernel<<<(2560 + 2048 + 255) / 256, 256, 0, stream>>>(W1, W2, W1f, W2f);
  prep_x_kernel<<<(N_NODES * XROW) / 256, 256, 0, stream>>>(x, xb);

  binscat_kernel<<<(N_EDGES + EPB - 1) / EPB, BTHREADS, 0, stream>>>(
      eidx, ea, bin_cursor, bkt);
  binscan_kernel<<<1, 256, 0, stream>>>(bin_cursor, bin_base);
  binsort_kernel<<<NBIN, 256, 0, stream>>>(bkt, bin_cursor, bin_base, csr, offsets);

  gmlp_kernel<<<NTILE, 256, 0, stream>>>(
      csr, offsets, (const uint4v*)xb, W1f, b1, W2f, b2, out);
}